// Round 8
// baseline (136.539 us; speedup 1.0000x reference)
//
#include <hip/hip_runtime.h>

// Problem dims (hard-coded in reference)
#define DD   768
#define NN   512
#define MM   512

#define PRE_K 2.88539008177792681472f   // 2*log2(e)

typedef _Float16 h8 __attribute__((ext_vector_type(8)));  // 8 f16 (4 VGPRs)
typedef __attribute__((ext_vector_type(4))) float f32x4;  // MFMA C/D

__device__ __forceinline__ float fexp(float x) { return __builtin_amdgcn_exp2f(x); }
__device__ __forceinline__ float frcp(float x) { return __builtin_amdgcn_rcpf(x); }
// tanh(x) = 1 - 2/(1 + e^{2x}); saturates correctly via exp2->inf/0 + rcp.
__device__ __forceinline__ float fast_tanh(float x) {
  return 1.0f - 2.0f * frcp(fexp(PRE_K * x) + 1.0f);
}
// Ledger: R13 keep HW trans. R14-R16: Q-fusion into main always lost. R17:
// cooperative mega-kernel catastrophic. R18: bounds(256,8) -> spills. R19(R6):
// main 44.8 @ occ40 ~= 45.4 @ occ30 -> main at trans-issue floor, FROZEN.
// R20(R7): BK 32->64 neutral -> GEMM interiors not barrier-bound; support mass
// is the 4-deep chain + prep's 16MB round-trip. R21(this): delete prep, do
// fp32->f16 split in-GEMM (values identical), transpose W1/W2 through an LDS
// scratch inside mfma1, fold T-init into mfma2 z=4. 4 kernels -> 3.

// fp32 -> f16 hi/lo split (pair covers ~21 mantissa bits)
__device__ __forceinline__ void splitf(float x, ushort& h, ushort& l) {
  const _Float16 hh = (_Float16)x;
  const _Float16 ll = (_Float16)(x - (float)hh);
  h = __builtin_bit_cast(unsigned short, hh);
  l = __builtin_bit_cast(unsigned short, ll);
}

__device__ __forceinline__ void split4(const float4 v, ushort4& h, ushort4& l) {
  splitf(v.x, h.x, l.x); splitf(v.y, h.y, l.y);
  splitf(v.z, h.z, l.z); splitf(v.w, h.w, l.w);
}

// ---- staged-LDS MFMA GEMM core, 32x64 tile, BK=64, on-the-fly convert ------
// AF32:  A source is fp32 rows (split in-register). else: pre-split f16 pair.
// BKIND: 1 = B fp32 rows [j][k-contig] (visual/W3); 2 = B fp32 [k][j] (W1/W2),
//        transposed through the Ts LDS scratch (coalesced in, column out).
// MFMA fragment values and accumulation order are bit-identical to the R7
// core (same splitf results, same hh/hl/[lh] kk-inner order).
#define BK2   64
#define LROW2 72           // padded LDS row stride (f16)
#define APL2  (32 * LROW2) // one A plane (ushorts)
#define BPL2  (64 * LROW2) // one B plane
#define TPAD  68           // fp32 transpose-scratch row stride (16B-aligned)

template <bool ALO, bool AF32, int BKIND>
__device__ __forceinline__ void gemm_core64u(
    ushort* __restrict__ As, ushort* __restrict__ Bs, float* __restrict__ Ts,
    const float* __restrict__ Af,
    const ushort* __restrict__ Ahg, const ushort* __restrict__ Alg,
    const float* __restrict__ Bf,
    int i0, int j0, int k0, int nsteps, f32x4* acc)
{
  const int tid = threadIdx.x;
  const int lane = tid & 63, wave = tid >> 6;
  const int r15 = lane & 15, quad = lane >> 4;
  const int wr = wave >> 1, wc = wave & 1;              // 2x2 wave grid
  const int fa = (wr * 16 + r15) * LROW2 + quad * 8;    // A frag offset
  const int fb = (wc * 32 + r15) * LROW2 + quad * 8;    // B frag base

  const int arow = tid >> 3;            // 0..31
  const int ks8  = (tid & 7) * 8;       // 0,8,...,56
  const int lwa  = arow * LROW2 + ks8;
  const size_t ga  = (size_t)(i0 + arow) * DD + k0 + ks8;
  // BKIND1: B rows arow, arow+32
  const size_t gb0 = (size_t)(j0 + arow) * DD + k0 + ks8;
  const size_t gb1 = (size_t)(j0 + arow + 32) * DD + k0 + ks8;
  const int lwb0 = arow * LROW2 + ks8;
  const int lwb1 = (arow + 32) * LROW2 + ks8;
  // BKIND2: phase1 rows kt+16q / cols j4; phase2 col tj, k-chunk tkc
  const int kt  = tid >> 4;             // 0..15
  const int j4  = (tid & 15) * 4;
  const int tj  = tid >> 2;             // 0..63
  const int tkc = (tid & 3) * 16;

  // prefetch registers
  float4 a0, a1; h8 pah, pal;
  float4 b0a, b0b, b1a, b1b;
  float4 w0, w1, w2, w3;

  auto loadS = [&](int s) {
    if constexpr (AF32) {
      a0 = *(const float4*)&Af[ga + (size_t)s * BK2];
      a1 = *(const float4*)&Af[ga + (size_t)s * BK2 + 4];
    } else {
      pah = *(const h8*)(Ahg + ga + (size_t)s * BK2);
      if (ALO) pal = *(const h8*)(Alg + ga + (size_t)s * BK2);
    }
    if constexpr (BKIND == 1) {
      b0a = *(const float4*)&Bf[gb0 + (size_t)s * BK2];
      b0b = *(const float4*)&Bf[gb0 + (size_t)s * BK2 + 4];
      b1a = *(const float4*)&Bf[gb1 + (size_t)s * BK2];
      b1b = *(const float4*)&Bf[gb1 + (size_t)s * BK2 + 4];
    } else {
      const size_t kb = (size_t)(k0 + s * BK2);
      w0 = *(const float4*)&Bf[(kb + kt)      * DD + j0 + j4];
      w1 = *(const float4*)&Bf[(kb + kt + 16) * DD + j0 + j4];
      w2 = *(const float4*)&Bf[(kb + kt + 32) * DD + j0 + j4];
      w3 = *(const float4*)&Bf[(kb + kt + 48) * DD + j0 + j4];
    }
  };

  auto stageA = [&](ushort* dst) {
    if constexpr (AF32) {
      ushort4 h0, l0, h1, l1;
      split4(a0, h0, l0); split4(a1, h1, l1);
      *(ushort4*)&dst[lwa]     = h0;
      *(ushort4*)&dst[lwa + 4] = h1;
      if (ALO) {
        *(ushort4*)&dst[APL2 + lwa]     = l0;
        *(ushort4*)&dst[APL2 + lwa + 4] = l1;
      }
    } else {
      *(h8*)&dst[lwa] = pah;
      if (ALO) *(h8*)&dst[APL2 + lwa] = pal;
    }
  };

  auto stageB1 = [&](ushort* dst) {
    ushort4 h0, l0, h1, l1;
    split4(b0a, h0, l0); split4(b0b, h1, l1);
    *(ushort4*)&dst[lwb0]            = h0;
    *(ushort4*)&dst[lwb0 + 4]        = h1;
    *(ushort4*)&dst[BPL2 + lwb0]     = l0;
    *(ushort4*)&dst[BPL2 + lwb0 + 4] = l1;
    split4(b1a, h0, l0); split4(b1b, h1, l1);
    *(ushort4*)&dst[lwb1]            = h0;
    *(ushort4*)&dst[lwb1 + 4]        = h1;
    *(ushort4*)&dst[BPL2 + lwb1]     = l0;
    *(ushort4*)&dst[BPL2 + lwb1 + 4] = l1;
  };

  auto stageTs = [&]() {
    *(float4*)&Ts[(kt)      * TPAD + j4] = w0;
    *(float4*)&Ts[(kt + 16) * TPAD + j4] = w1;
    *(float4*)&Ts[(kt + 32) * TPAD + j4] = w2;
    *(float4*)&Ts[(kt + 48) * TPAD + j4] = w3;
  };

  auto phase2 = [&](ushort* dst) {   // Ts column -> split -> B planes
    ushort* db = &dst[tj * LROW2 + tkc];
    ushort* dl = db + BPL2;
    #pragma unroll
    for (int c4 = 0; c4 < 4; ++c4) {
      const int kb = tkc + c4 * 4;
      ushort4 h, l;
      splitf(Ts[(kb + 0) * TPAD + tj], h.x, l.x);
      splitf(Ts[(kb + 1) * TPAD + tj], h.y, l.y);
      splitf(Ts[(kb + 2) * TPAD + tj], h.z, l.z);
      splitf(Ts[(kb + 3) * TPAD + tj], h.w, l.w);
      *(ushort4*)&db[c4 * 4] = h;
      *(ushort4*)&dl[c4 * 4] = l;
    }
  };

  // prologue: stage step 0 into buffer 0
  loadS(0);
  stageA(As);
  if constexpr (BKIND == 1) stageB1(Bs);
  else {
    stageTs();
    __syncthreads();
    phase2(Bs);
  }
  __syncthreads();

  int p = 0;
  for (int s = 0; s < nsteps; ++s) {
    const bool more = (s + 1 < nsteps);
    if (more) loadS(s + 1);       // globals in flight under the MFMAs
    ushort* Ac = As + p * 2 * APL2;
    ushort* Bc = Bs + p * 2 * BPL2;
    #pragma unroll
    for (int kk = 0; kk < 2; ++kk) {    // two 32-K sub-chunks, in K order
      const int fo = kk * 32;
      const h8 a_h = *(const h8*)&Ac[fa + fo];
      h8 a_l; if (ALO) a_l = *(const h8*)&Ac[APL2 + fa + fo];
      h8 b_h[2], b_l[2];
      #pragma unroll
      for (int c = 0; c < 2; ++c) {
        b_h[c] = *(const h8*)&Bc[fb + c * 16 * LROW2 + fo];
        b_l[c] = *(const h8*)&Bc[BPL2 + fb + c * 16 * LROW2 + fo];
      }
      #pragma unroll
      for (int c = 0; c < 2; ++c)
        acc[c] = __builtin_amdgcn_mfma_f32_16x16x32_f16(a_h, b_h[c], acc[c], 0, 0, 0);
      #pragma unroll
      for (int c = 0; c < 2; ++c)
        acc[c] = __builtin_amdgcn_mfma_f32_16x16x32_f16(a_h, b_l[c], acc[c], 0, 0, 0);
      if (ALO) {
        #pragma unroll
        for (int c = 0; c < 2; ++c)
          acc[c] = __builtin_amdgcn_mfma_f32_16x16x32_f16(a_l, b_h[c], acc[c], 0, 0, 0);
      }
    }
    ushort* An = As + (p ^ 1) * 2 * APL2;
    ushort* Bn = Bs + (p ^ 1) * 2 * BPL2;
    if (more) {
      stageA(An);
      if constexpr (BKIND == 1) stageB1(Bn);
      else stageTs();
    }
    if constexpr (BKIND == 2) {
      __syncthreads();            // Ts complete (also: everyone done with buf p)
      if (more) phase2(Bn);
    }
    __syncthreads();
    p ^= 1;
  }
}

// z=0: A=text@W1 -> Ah/Al(f16)  z=1: kw2t=PRE_K*text@W2  z=2: kw3v=PRE_K*visual@W3^T
// Self-sufficient: reads raw fp32 inputs, converts/transposes in-kernel.
// grid (12, 16, 3) = 576 blocks; 12 K-steps of 64. LDS 71.9KB -> 2 blocks/CU.
__global__ __launch_bounds__(256) void mfma1_kernel(
    const float* __restrict__ text, const float* __restrict__ visual,
    const float* __restrict__ W1, const float* __restrict__ W2,
    const float* __restrict__ W3,
    ushort* __restrict__ Ah, ushort* __restrict__ Al,
    float* __restrict__ kw2t, float* __restrict__ kw3v)
{
  __shared__ ushort As[2 * 2 * APL2];   // 18432 B
  __shared__ ushort Bs[2 * 2 * BPL2];   // 36864 B
  __shared__ float  Ts[64 * TPAD];      // 17408 B transpose scratch

  const int z  = blockIdx.z;
  const int j0 = blockIdx.x * 64;
  const int i0 = blockIdx.y * 32;

  f32x4 acc[2];
  acc[0] = (f32x4){0.f, 0.f, 0.f, 0.f};
  acc[1] = (f32x4){0.f, 0.f, 0.f, 0.f};

  if (z == 0)
    gemm_core64u<true,  true, 2>(As, Bs, Ts, text,   nullptr, nullptr, W1,
                                 i0, j0, 0, DD / BK2, acc);
  else if (z == 1)
    gemm_core64u<false, true, 2>(As, Bs, Ts, text,   nullptr, nullptr, W2,
                                 i0, j0, 0, DD / BK2, acc);
  else
    gemm_core64u<false, true, 1>(As, Bs, Ts, visual, nullptr, nullptr, W3,
                                 i0, j0, 0, DD / BK2, acc);

  const int lane = threadIdx.x & 63, wave = threadIdx.x >> 6;
  const int r15 = lane & 15, quad = lane >> 4;
  const int wr = wave >> 1, wc = wave & 1;
  // C/D layout: col=lane&15 (B row j), row=quad*4+reg (A row i)
  if (z == 0) {
    #pragma unroll
    for (int c = 0; c < 2; ++c)
      #pragma unroll
      for (int r = 0; r < 4; ++r) {
        const size_t o = (size_t)(i0 + wr * 16 + quad * 4 + r) * DD
                       + j0 + wc * 32 + c * 16 + r15;
        splitf(acc[c][r], Ah[o], Al[o]);
      }
  } else {
    float* Out = (z == 1) ? kw2t : kw3v;
    #pragma unroll
    for (int c = 0; c < 2; ++c)
      #pragma unroll
      for (int r = 0; r < 4; ++r)
        Out[(size_t)(i0 + wr * 16 + quad * 4 + r) * DD + j0 + wc * 32 + c * 16 + r15] =
            acc[c][r] * PRE_K;
  }
}

// z 0..3: Q[z] = A @ visual^T over K quarter z (B = raw visual, split on-fly).
// z == 4: T-init — out[n][:] = T[n] (128 blocks x 2 iterations of the proven
// 2-row reduction body; per-row numerics identical to the old prep).
// grid (8, 16, 5) = 640 blocks.
__global__ __launch_bounds__(256) void mfma2_kernel(
    const ushort* __restrict__ Ah, const ushort* __restrict__ Al,
    const float* __restrict__ visual, const float* __restrict__ text,
    float* __restrict__ Q, float* __restrict__ out)
{
  __shared__ ushort As[2 * 2 * APL2];
  __shared__ ushort Bs[2 * 2 * BPL2];

  const int t = threadIdx.x;
  if (blockIdx.z == 4) {
    float* red = (float*)As;            // 256 floats scratch
    const int bid  = blockIdx.y * 8 + blockIdx.x;   // 0..127
    const int half = t >> 7;
    const int lt   = t & 127;
    #pragma unroll
    for (int u2 = 0; u2 < 2; ++u2) {
      const int n0 = (bid + 128 * u2) * 2;
      const float* tr = text + (size_t)(n0 + half) * DD;
      float s = 0.f;
      #pragma unroll
      for (int i = 0; i < DD / 128; ++i) s += tr[lt + i * 128];
      red[t] = s;
      __syncthreads();
      #pragma unroll
      for (int st = 64; st > 0; st >>= 1) {
        if (lt < st) red[t] += red[t + st];
        __syncthreads();
      }
      const float Tn = red[half << 7];
      float4 o; o.x = Tn; o.y = Tn; o.z = Tn; o.w = Tn;
      *(float4*)&out[(size_t)(n0 + half) * MM + lt * 4] = o;
      __syncthreads();                  // red reuse guard
    }
    return;
  }

  const int z  = blockIdx.z;
  const int j0 = blockIdx.x * 64;
  const int i0 = blockIdx.y * 32;

  f32x4 acc[2];
  acc[0] = (f32x4){0.f, 0.f, 0.f, 0.f};
  acc[1] = (f32x4){0.f, 0.f, 0.f, 0.f};
  gemm_core64u<true, false, 1>(As, Bs, nullptr, nullptr, Ah, Al, visual,
                               i0, j0, z * (DD / 4), (DD / 4) / BK2, acc);

  const int lane = t & 63, wave = t >> 6;
  const int r15 = lane & 15, quad = lane >> 4;
  const int wr = wave >> 1, wc = wave & 1;
  float* Qp = Q + (size_t)z * NN * MM;
  #pragma unroll
  for (int c = 0; c < 2; ++c)
    #pragma unroll
    for (int r = 0; r < 4; ++r)
      Qp[(size_t)(i0 + wr * 16 + quad * 4 + r) * MM + j0 + wc * 32 + c * 16 + r15] =
          acc[c][r];
}

// ---- main fused kernel (R19/R6-proven, FROZEN) -----------------------------
#define DCH    32
#define DRANGE 192
#define MLDW   36

__global__ __launch_bounds__(256, 4) void main_kernel(
    const float* __restrict__ text, const float* __restrict__ kw2t,
    const float* __restrict__ kw3v, const float* __restrict__ Q,
    float* __restrict__ out)
{
  __shared__ float sbuf[2][64 * MLDW];   // 2 x 9216 B = 18432 B

  const int tid = threadIdx.x;
  const int nl = tid >> 4;
  const int ml = tid & 15;
  const int n0 = blockIdx.y * 16;
  const int m0 = blockIdx.x * 32;
  const int z  = blockIdx.z;
  const int n  = n0 + nl;
  const int mA = m0 + ml, mB = mA + 16;
  const int dbase = z * DRANGE;

  float cA = 0.f, cB = 0.f;
  #pragma unroll
  for (int zz = 0; zz < 4; ++zz) {
    const float* q = Q + (size_t)zz * NN * MM + (size_t)n * MM;
    cA += q[mA]; cB += q[mB];
  }
  cA = fast_tanh(cA); cB = fast_tanh(cB);

  float4 aA = {0.f, 0.f, 0.f, 0.f};
  float4 aB = {0.f, 0.f, 0.f, 0.f};

  // staging: 64 rows (text 0..15 | kw2t 16..31 | kw3v 32..63) x 32 cols
  const int srow = tid >> 3;              // 0..31
  const int sc   = (tid & 7) << 2;        // 0,4,...,28
  const float* g1 = (srow < 16)
      ? &text[(size_t)(n0 + srow) * DD + dbase + sc]
      : &kw2t[(size_t)(n0 + srow - 16) * DD + dbase + sc];
  const float* g3 = &kw3v[(size_t)(m0 + srow) * DD + dbase + sc];
  const int w1 = srow * MLDW + sc;          // rows 0..31 (text | kw2t)
  const int w3 = (32 + srow) * MLDW + sc;   // rows 32..63 (kw3v, 32 rows)

  // prologue: stage chunk 0 into buffer 0
  float4 r1 = *(const float4*)g1;
  float4 r3 = *(const float4*)g3;
  int p = 0;
  *(float4*)&sbuf[0][w1] = r1;
  *(float4*)&sbuf[0][w3] = r3;
  __syncthreads();

  #pragma unroll
  for (int c = 0; c < DRANGE / DCH; ++c) {   // 6 chunks
    const bool more = (c + 1 < DRANGE / DCH);
    if (more) {  // prefetch next chunk; compute below hides latency
      r1 = *(const float4*)(g1 + (c + 1) * DCH);
      r3 = *(const float4*)(g3 + (c + 1) * DCH);
    }
    const float* bp = sbuf[p];
    #pragma unroll 4
    for (int j = 0; j < DCH; j += 4) {
      const float4 tv  = *(const float4*)&bp[nl * MLDW + j];
      const float4 w2v = *(const float4*)&bp[(16 + nl) * MLDW + j];
      const float4 w3A = *(const float4*)&bp[(32 + ml) * MLDW + j];
      const float4 w3B = *(const float4*)&bp[(48 + ml) * MLDW + j];
      aA.x = fmaf(tv.x, frcp(fexp(fmaf(w3A.x, cA, w2v.x)) + 1.0f), aA.x);
      aA.y = fmaf(tv.y, frcp(fexp(fmaf(w3A.y, cA, w2v.y)) + 1.0f), aA.y);
      aA.z = fmaf(tv.z, frcp(fexp(fmaf(w3A.z, cA, w2v.z)) + 1.0f), aA.z);
      aA.w = fmaf(tv.w, frcp(fexp(fmaf(w3A.w, cA, w2v.w)) + 1.0f), aA.w);
      aB.x = fmaf(tv.x, frcp(fexp(fmaf(w3B.x, cB, w2v.x)) + 1.0f), aB.x);
      aB.y = fmaf(tv.y, frcp(fexp(fmaf(w3B.y, cB, w2v.y)) + 1.0f), aB.y);
      aB.z = fmaf(tv.z, frcp(fexp(fmaf(w3B.z, cB, w2v.z)) + 1.0f), aB.z);
      aB.w = fmaf(tv.w, frcp(fexp(fmaf(w3B.w, cB, w2v.w)) + 1.0f), aB.w);
    }
    if (more) {
      const int q = p ^ 1;
      *(float4*)&sbuf[q][w1] = r1;
      *(float4*)&sbuf[q][w3] = r3;
    }
    __syncthreads();   // single barrier per chunk
    p ^= 1;
  }

  float* op = out + (size_t)n * MM;
  unsafeAtomicAdd(&op[mA], -2.0f * ((aA.x + aA.y) + (aA.z + aA.w)));
  unsafeAtomicAdd(&op[mB], -2.0f * ((aB.x + aB.y) + (aB.z + aB.w)));
}

// ---- launcher --------------------------------------------------------------
extern "C" void kernel_launch(void* const* d_in, const int* in_sizes, int n_in,
                              void* d_out, int out_size, void* d_ws, size_t ws_size,
                              hipStream_t stream) {
  const float* text   = (const float*)d_in[0];
  const float* visual = (const float*)d_in[1];
  const float* W1     = (const float*)d_in[2];
  const float* W2     = (const float*)d_in[3];
  const float* W3     = (const float*)d_in[4];
  float* out = (float*)d_out;

  // Workspace (8.5 MB now — prep buffers deleted):
  //   Ah/Al : f16 hi/lo of A = text@W1   (2 x 768 KB)
  //   kw2t  : fp32 PRE_K * text@W2       (1.5 MB)
  //   kw3v  : fp32 PRE_K * visual@W3^T   (1.5 MB)
  //   Q     : fp32 K-quarter partials    (4 MB)
  char* base = (char*)d_ws;
  ushort* Ah   = (ushort*)(base);
  ushort* Al   = (ushort*)(base + 786432);
  float*  kw2t = (float*) (base + 1572864);
  float*  kw3v = (float*) (base + 3145728);
  float*  Q    = (float*) (base + 4718592);

  hipLaunchKernelGGL(mfma1_kernel, dim3(DD / 64, NN / 32, 3), dim3(256), 0, stream,
                     text, visual, W1, W2, W3, Ah, Al, kw2t, kw3v);
  hipLaunchKernelGGL(mfma2_kernel, dim3(MM / 64, NN / 32, 5), dim3(256), 0, stream,
                     Ah, Al, visual, text, Q, out);
  hipLaunchKernelGGL(main_kernel, dim3(MM / 32, NN / 16, 4), dim3(256), 0, stream,
                     text, kw2t, kw3v, Q, out);
}